// Round 7
// baseline (123.747 us; speedup 1.0000x reference)
//
#include <hip/hip_runtime.h>

// B=2, S=2048, E=1024, H=16.  Output tuple:
//   out  [B,S,E]   = 16 MiB f32 (rows identical per batch)
//   attn [B,H,S,S] = 512 MiB f32 (constant 1/2048)
// HBM-write-BW bound; floor ~88 us incl. ~42 MB reads at 6.8 TB/s.
//
// 3 kernels (minimum: colsum -> needs-all-part1 -> needs-all-z):
//  K1: 256 colsum blocks (value -> part1)                    || fill 1280 blk
//  K2: 32 blocks (b, 64-col grp): redundant vbar reduce (512 KiB cached) +
//      z64 = vbar@Wv[:,64] + bv  (256 KiB Wv slice)          || fill 1484 blk
//  K3: 32 blocks (b, 64-col grp): orow64 = z@Wo[:,64]+bo ->
//      broadcast 64-col stripe to 2048 rows                  || fill 1332 blk
// Fill blocks write 128 KiB each (4096 total = 512 MiB).
// All reductions fixed-order -> deterministic.

typedef float floatx4 __attribute__((ext_vector_type(4)));

#define ATTN_BASE4 1048576LL      // B*S*E/4 (float4 units)
#define K1_FILLB   1280
#define K2_FILLB   1484
#define K3_FILLB   1332           // sum = 4096 blocks x 8192 f4 = attn

__device__ __forceinline__ void fill_at(float* __restrict__ out, long long f4base) {
    floatx4* o4 = (floatx4*)out;
    const floatx4 av = (floatx4)(1.0f / 2048.0f);   // exact softmax of const scores
    long long base = f4base + threadIdx.x;
    #pragma unroll
    for (int it = 0; it < 32; ++it)
        __builtin_nontemporal_store(av, &o4[base + it * 256]);
}

// ---------------------------------------------------------------------------
// K1: blocks 0..255 -> partial column sums of value (2 batches x 128 splits
// of 16 rows); rest -> fill.
__global__ void __launch_bounds__(256)
k1_colsum_fill(const float* __restrict__ value,
               float* __restrict__ part1,
               float* __restrict__ out) {
    int blk = blockIdx.x, t = threadIdx.x;
    if (blk < 256) {
        int b = blk >> 7, sp = blk & 127;
        const floatx4* v4 = (const floatx4*)value;
        floatx4 acc = (floatx4)0.0f;
        int rowbase = b * 2048 + sp * 16;
        #pragma unroll
        for (int r = 0; r < 16; ++r)
            acc += v4[(size_t)(rowbase + r) * 256 + t];
        ((floatx4*)part1)[(size_t)(b * 128 + sp) * 256 + t] = acc;
    } else {
        fill_at(out, ATTN_BASE4 + (long long)(blk - 256) * 8192);
    }
}

// ---------------------------------------------------------------------------
// K2: blocks 0..31 -> (b = blk>>4, 64-col group): redundant vbar reduce,
// then z[cols] = vbar @ Wv[:,cols] + bv[cols]; rest -> fill.
__global__ void __launch_bounds__(256)
k2_z_fill(const float* __restrict__ part1,
          const float* __restrict__ Wv, const float* __restrict__ bv,
          float* __restrict__ z,
          float* __restrict__ out) {
    int blk = blockIdx.x, t = threadIdx.x;
    if (blk < 32) {
        __shared__ __align__(16) float vbar[1024];
        __shared__ float red[256];
        int b = blk >> 4, cg = blk & 15, e0 = cg * 64;

        // vbar = mean_s value (reduce 128 partials; 512 KiB, L2/L3-resident)
        const floatx4* p4 = (const floatx4*)part1 + (size_t)b * 128 * 256;
        floatx4 acc = (floatx4)0.0f;
        #pragma unroll 8
        for (int sp = 0; sp < 128; ++sp)
            acc += p4[sp * 256 + t];
        ((floatx4*)vbar)[t] = acc * (1.0f / 2048.0f);
        __syncthreads();

        // z slice: 64 cols x 4 k-segments of 256 (wave reads 256 B contiguous)
        int col = t & 63, seg = t >> 6;
        const float* wcol = Wv + e0 + col;
        float part = 0.f;
        int k0 = seg * 256;
        #pragma unroll 8
        for (int kk = 0; kk < 256; ++kk) {
            int k = k0 + kk;
            part += vbar[k] * wcol[(size_t)k * 1024];
        }
        red[t] = part;
        __syncthreads();
        if (t < 64) {
            float s = bv[e0 + t];
            #pragma unroll
            for (int g = 0; g < 4; ++g) s += red[g * 64 + t];
            z[b * 1024 + e0 + t] = s;
        }
    } else {
        fill_at(out, ATTN_BASE4 + (long long)(K1_FILLB + (blk - 32)) * 8192);
    }
}

// ---------------------------------------------------------------------------
// K3: blocks 0..31 -> (b, 64-col group): orow[cols] = z@Wo[:,cols]+bo,
// broadcast the 64-col stripe to all 2048 rows; rest -> fill.
__global__ void __launch_bounds__(256)
k3_orow_bcast_fill(const float* __restrict__ z,
                   const float* __restrict__ Wo, const float* __restrict__ bo,
                   float* __restrict__ out) {
    int blk = blockIdx.x, t = threadIdx.x;
    if (blk < 32) {
        __shared__ __align__(16) float zsh[1024];
        __shared__ float red[256];
        __shared__ __align__(16) float orow[64];
        int b = blk >> 4, cg = blk & 15, e0 = cg * 64;

        ((floatx4*)zsh)[t] = ((const floatx4*)z)[b * 256 + t];
        __syncthreads();

        int col = t & 63, seg = t >> 6;
        const float* wcol = Wo + e0 + col;
        float part = 0.f;
        int k0 = seg * 256;
        #pragma unroll 8
        for (int kk = 0; kk < 256; ++kk) {
            int k = k0 + kk;
            part += zsh[k] * wcol[(size_t)k * 1024];
        }
        red[t] = part;
        __syncthreads();
        if (t < 64) {
            float s = bo[e0 + t];
            #pragma unroll
            for (int g = 0; g < 4; ++g) s += red[g * 64 + t];
            orow[t] = s;
        }
        __syncthreads();

        // broadcast: 64 cols = 16 float4; 256 threads = 16 quads x 16 row-lanes
        int q = t & 15, rl = t >> 4;
        floatx4 w = ((const floatx4*)orow)[q];
        floatx4* o4 = (floatx4*)out;
        size_t cbase = (size_t)(e0 >> 2) + q;
        #pragma unroll 8
        for (int r = rl; r < 2048; r += 16)
            __builtin_nontemporal_store(w, &o4[((size_t)b * 2048 + r) * 256 + cbase]);
    } else {
        fill_at(out, ATTN_BASE4
                     + (long long)(K1_FILLB + K2_FILLB + (blk - 32)) * 8192);
    }
}

extern "C" void kernel_launch(void* const* d_in, const int* in_sizes, int n_in,
                              void* d_out, int out_size, void* d_ws, size_t ws_size,
                              hipStream_t stream) {
    // inputs: query(0) key(1) value(2) Wq(3) bq(4) Wk(5) bk(6) Wv(7) bv(8) Wo(9) bo(10)
    const float* value = (const float*)d_in[2];
    const float* Wv    = (const float*)d_in[7];
    const float* bv    = (const float*)d_in[8];
    const float* Wo    = (const float*)d_in[9];
    const float* bo    = (const float*)d_in[10];
    float* out = (float*)d_out;

    float* part1 = (float*)d_ws;        // 262144 floats (1 MiB)
    float* zbuf  = part1 + 262144;      // 2048 floats

    k1_colsum_fill    <<<256 + K1_FILLB, 256, 0, stream>>>(value, part1, out);
    k2_z_fill         <<< 32 + K2_FILLB, 256, 0, stream>>>(part1, Wv, bv, zbuf, out);
    k3_orow_bcast_fill<<< 32 + K3_FILLB, 256, 0, stream>>>(zbuf, Wo, bo, out);
}

// Round 8
// 109.183 us; speedup vs baseline: 1.1334x; 1.1334x over previous
//
#include <hip/hip_runtime.h>

// B=2, S=2048, E=1024, H=16.  out [B,S,E] = 16 MiB f32 (rows identical per
// batch); attn [B,H,S,S] = 512 MiB f32 (constant 1/2048). Write-BW bound:
// 596 MB total traffic @ 6.8 TB/s => ~88 us floor.
//
// R3-R7 lesson: kernel duration = max over CUs of per-CU traffic; with one
// co-resident generation, per-BLOCK traffic must be uniform. Every block in
// every kernel here moves ~64-84 KiB.
//   K1: 256 colsum blk (68 KB)                                  || fill
//   K2: 128 zpart blk (b, k-slice 32, e-half): 16+64 KB         || fill
//   K3: 64 z-finish blk (4 KB, negligible)                      || fill
//   K4: 1024 bcast blk (b, col-grp 16, row-rng 256): 68+16 KB   || fill
// Fill: 16 KiB chunks (4 float4/thread), static grid-stride shares.
// All reductions fixed-order -> deterministic.

typedef float floatx4 __attribute__((ext_vector_type(4)));
typedef float floatx2 __attribute__((ext_vector_type(2)));

#define ATTN_BASE4 1048576LL   // B*S*E/4 in float4 units
// fill chunk = 1024 float4 = 16 KiB; 32768 chunks = 512 MiB total
#define O1 0
#define F1 7168
#define O2 7168
#define F2 8800
#define O3 15968
#define F3 9380
#define O4 25348
#define F4 7420                // O4+F4 = 32768

__device__ __forceinline__ void fill_chunks(float* __restrict__ out,
                                            int fb, int nf, int O, int F) {
    floatx4* o4 = (floatx4*)out;
    const floatx4 av = (floatx4)(1.0f / 2048.0f);  // exact softmax of const scores
    for (int c = fb; c < F; c += nf) {
        long long base = ATTN_BASE4 + ((long long)(O + c) << 10) + threadIdx.x;
        #pragma unroll
        for (int it = 0; it < 4; ++it)
            __builtin_nontemporal_store(av, &o4[base + it * 256]);
    }
}

// ---------------------------------------------------------------------------
// K1: partial column sums of value (2 batches x 128 splits of 16 rows).
__global__ void __launch_bounds__(256)
k1_colsum_fill(const float* __restrict__ value,
               float* __restrict__ part1, float* __restrict__ out) {
    int blk = blockIdx.x, t = threadIdx.x;
    if (blk < 256) {
        int b = blk >> 7, sp = blk & 127;
        const floatx4* v4 = (const floatx4*)value;
        floatx4 acc = (floatx4)0.0f;
        int rowbase = b * 2048 + sp * 16;
        #pragma unroll
        for (int r = 0; r < 16; ++r)
            acc += v4[(size_t)(rowbase + r) * 256 + t];
        ((floatx4*)part1)[(size_t)(b * 128 + sp) * 256 + t] = acc;
    } else {
        fill_chunks(out, blk - 256, 1792, O1, F1);
    }
}

// ---------------------------------------------------------------------------
// K2: zpart[b][ks][e] = sum_{k in ks-slice} vbar[k]*Wv[k][e], for an e-half.
// Block = (b, ks of 32 k's, eh): slice-vbar from part1 (16 KB) + 32 Wv rows
// over 512 e (64 KB).
__global__ void __launch_bounds__(256)
k2_zpart_fill(const float* __restrict__ part1, const float* __restrict__ Wv,
              float* __restrict__ zpart, float* __restrict__ out) {
    int blk = blockIdx.x, t = threadIdx.x;
    if (blk < 128) {
        __shared__ float red[256];
        __shared__ float vsl[32];
        int b = blk >> 6, r = blk & 63, ks = r >> 1, eh = r & 1;
        int k0 = ks * 32;
        int kl = t & 31, sg = t >> 5;
        float s = 0.f;
        #pragma unroll
        for (int i = 0; i < 16; ++i) {
            int sp = sg * 16 + i;
            s += part1[(size_t)(b * 128 + sp) * 1024 + k0 + kl];
        }
        red[t] = s;
        __syncthreads();
        if (t < 32) {
            float v = 0.f;
            #pragma unroll
            for (int g = 0; g < 8; ++g) v += red[g * 32 + t];
            vsl[t] = v * (1.0f / 2048.0f);
        }
        __syncthreads();
        int e2 = eh * 512 + 2 * t;
        floatx2 acc = (floatx2)0.0f;
        #pragma unroll 8
        for (int kk = 0; kk < 32; ++kk) {
            floatx2 w = *(const floatx2*)&Wv[(size_t)(k0 + kk) * 1024 + e2];
            acc += vsl[kk] * w;
        }
        *(floatx2*)&zpart[(size_t)(b * 32 + ks) * 1024 + e2] = acc;
    } else {
        fill_chunks(out, blk - 128, 1920, O2, F2);
    }
}

// ---------------------------------------------------------------------------
// K3: z[b][e] = bv[e] + sum_seg zpart[b][seg][e].  64 tiny blocks (b, e-grp 32).
__global__ void __launch_bounds__(256)
k3_zfin_fill(const float* __restrict__ zpart, const float* __restrict__ bv,
             float* __restrict__ z, float* __restrict__ out) {
    int blk = blockIdx.x, t = threadIdx.x;
    if (blk < 64) {
        int b = blk >> 5, es = blk & 31, e0 = es * 32;
        if (t < 32) {
            float s = bv[e0 + t];
            #pragma unroll 8
            for (int seg = 0; seg < 32; ++seg)
                s += zpart[(size_t)(b * 32 + seg) * 1024 + e0 + t];
            z[b * 1024 + e0 + t] = s;
        }
    } else {
        fill_chunks(out, blk - 64, 1984, O3, F3);
    }
}

// ---------------------------------------------------------------------------
// K4: block (b, col-grp of 16, row-range of 256): orow[cg] = z@Wo[:,cg]+bo
// (redundant per row-range; Wo slice L3-served), broadcast 256 rows x 16 cols.
__global__ void __launch_bounds__(256)
k4_orow_bcast_fill(const float* __restrict__ z, const float* __restrict__ Wo,
                   const float* __restrict__ bo, float* __restrict__ out) {
    int blk = blockIdx.x, t = threadIdx.x;
    if (blk < 1024) {
        __shared__ __align__(16) float zsh[1024];
        __shared__ float red[256];
        __shared__ __align__(16) float orow[16];
        int b = blk >> 9, r = blk & 511, cg = r >> 3, rr = r & 7;
        int e0 = cg * 16;
        ((floatx4*)zsh)[t] = ((const floatx4*)z)[b * 256 + t];
        __syncthreads();
        int eo = e0 + (t & 15), sg = t >> 4;
        float part = 0.f;
        int eb = sg * 64;
        #pragma unroll 8
        for (int ee = 0; ee < 64; ++ee) {
            int e = eb + ee;
            part += zsh[e] * Wo[(size_t)e * 1024 + eo];
        }
        red[t] = part;
        __syncthreads();
        if (t < 16) {
            float o = bo[e0 + t];
            #pragma unroll
            for (int g = 0; g < 16; ++g) o += red[g * 16 + t];
            orow[t] = o;
        }
        __syncthreads();
        int q = t & 3, rl = t >> 2;
        floatx4 w = ((const floatx4*)orow)[q];
        floatx4* o4 = (floatx4*)out;
        size_t cb = (size_t)(e0 >> 2) + q;
        int rbase = rr * 256;
        #pragma unroll
        for (int i = 0; i < 4; ++i) {
            int row = rbase + i * 64 + rl;
            __builtin_nontemporal_store(w, &o4[((size_t)b * 2048 + row) * 256 + cb]);
        }
    } else {
        fill_chunks(out, blk - 1024, 1024, O4, F4);
    }
}

extern "C" void kernel_launch(void* const* d_in, const int* in_sizes, int n_in,
                              void* d_out, int out_size, void* d_ws, size_t ws_size,
                              hipStream_t stream) {
    // inputs: query(0) key(1) value(2) Wq(3) bq(4) Wk(5) bk(6) Wv(7) bv(8) Wo(9) bo(10)
    const float* value = (const float*)d_in[2];
    const float* Wv    = (const float*)d_in[7];
    const float* bv    = (const float*)d_in[8];
    const float* Wo    = (const float*)d_in[9];
    const float* bo    = (const float*)d_in[10];
    float* out = (float*)d_out;

    float* part1 = (float*)d_ws;        // 262144 floats (1 MiB)
    float* zpart = part1 + 262144;      // 2*32*1024 = 65536 floats (256 KiB)
    float* zbuf  = zpart + 65536;       // 2048 floats

    k1_colsum_fill    <<<2048, 256, 0, stream>>>(value, part1, out);
    k2_zpart_fill     <<<2048, 256, 0, stream>>>(part1, Wv, zpart, out);
    k3_zfin_fill      <<<2048, 256, 0, stream>>>(zpart, bv, zbuf, out);
    k4_orow_bcast_fill<<<2048, 256, 0, stream>>>(zbuf, Wo, bo, out);
}